// Round 1
// baseline (2653.081 us; speedup 1.0000x reference)
//
#include <hip/hip_runtime.h>
#include <math.h>

#define BB 8
#define SS 4096
#define DD 768
#define MM 64
#define FFN 3072
#define HH 12
#define HDH 64
#define EPSF 1e-5f
#define CCH 8            // S-chunks for dispatch
#define SCHUNK (SS/CCH)  // 512
#define ISPL 4
#define KI (DD/ISPL)     // 192
#define OSPL 16
#define KO (FFN/OSPL)    // 192
#define TS4 256          // tokens per combine block

__device__ __forceinline__ float wave_reduce_sum(float v) {
    #pragma unroll
    for (int off = 32; off > 0; off >>= 1)
        v += __shfl_xor(v, off, 64);
    return v;
}

// ---- normalize slots: sl[m,d] = slots[m,d] * scale[m] / max(||slots[m]||, eps)
__global__ __launch_bounds__(64) void k_slots(const float* __restrict__ slots,
                                              const float* __restrict__ scale,
                                              float* __restrict__ sl) {
    int m = blockIdx.x;
    int l = threadIdx.x;
    float s = 0.f;
    #pragma unroll
    for (int k = 0; k < DD/64; ++k) {
        float v = slots[m*DD + k*64 + l];
        s += v*v;
    }
    s = wave_reduce_sum(s);
    float fac = scale[m] / fmaxf(sqrtf(s), EPSF);
    #pragma unroll
    for (int k = 0; k < DD/64; ++k)
        sl[m*DD + k*64 + l] = slots[m*DD + k*64 + l] * fac;
}

// ---- per-token factors: frms = rsqrt(mean(x^2)+eps); fnt = frms / max(frms*||x*w||, eps)
__global__ __launch_bounds__(256) void k_tok(const float* __restrict__ x,
                                             const float* __restrict__ nw,
                                             float* __restrict__ frms,
                                             float* __restrict__ fnt) {
    int t = blockIdx.x * 4 + (threadIdx.x >> 6);
    int l = threadIdx.x & 63;
    const float* xr = x + (size_t)t * DD;
    float s1 = 0.f, s2 = 0.f;
    #pragma unroll
    for (int k = 0; k < DD/64; ++k) {
        float v  = xr[k*64 + l];
        float vw = v * nw[k*64 + l];
        s1 += v*v;
        s2 += vw*vw;
    }
    s1 = wave_reduce_sum(s1);
    s2 = wave_reduce_sum(s2);
    if (l == 0) {
        float r   = 1.0f / sqrtf(s1 / (float)DD + EPSF);
        float nrm = r * sqrtf(s2);
        frms[t] = r;
        fnt[t]  = r / fmaxf(nrm, EPSF);
    }
}

// ---- dispatch attention, partial (no max needed: |logit| <= 1 by Cauchy-Schwarz)
__global__ __launch_bounds__(256) void k_dispatch(const float* __restrict__ x,
        const float* __restrict__ sl, const float* __restrict__ nw,
        const float* __restrict__ frms, const float* __restrict__ fnt,
        float* __restrict__ pl_part, float* __restrict__ acc_part) {
    int bid = blockIdx.x;                 // B*H*CCH
    int b   = bid / (HH*CCH);
    int rem = bid % (HH*CCH);
    int h   = rem / CCH;
    int c   = rem % CCH;
    int wave = threadIdx.x >> 6;
    int l    = threadIdx.x & 63;

    // lane l owns slot l: its head-slice of sl in registers
    float slreg[64];
    #pragma unroll
    for (int k = 0; k < 16; ++k) {
        const float4 v = *(const float4*)&sl[(size_t)l*DD + h*HDH + 4*k];
        slreg[4*k+0] = v.x; slreg[4*k+1] = v.y;
        slreg[4*k+2] = v.z; slreg[4*k+3] = v.w;
    }
    float wl = nw[h*HDH + l];
    float acc[64];
    #pragma unroll
    for (int m = 0; m < 64; ++m) acc[m] = 0.f;
    float plr = 0.f;

    for (int ti = wave; ti < SCHUNK; ti += 4) {
        int t = b*SS + c*SCHUNK + ti;
        float xv   = x[(size_t)t*DD + h*HDH + l];
        float base = xv * wl;
        float ntv  = base * fnt[t];   // normalized-token component (d = lane)
        float xrv  = base * frms[t];  // rms-normed value component (d = lane)
        float lg = 0.f;
        #pragma unroll
        for (int j = 0; j < 64; ++j)
            lg += slreg[j] * __shfl(ntv, j, 64);
        float p = expf(lg);           // lane l: exp(logit[slot l])
        plr += p;
        #pragma unroll
        for (int m = 0; m < 64; ++m)
            acc[m] += __shfl(p, m, 64) * xrv;   // acc[slot m][d=lane]
    }

    __shared__ float red[4][64];
    __shared__ float ared[4][16][64];
    red[wave][l] = plr;
    __syncthreads();
    if (threadIdx.x < 64) {
        float tot = red[0][l] + red[1][l] + red[2][l] + red[3][l];
        pl_part[(size_t)bid*MM + l] = tot;
    }
    #pragma unroll
    for (int mc = 0; mc < 4; ++mc) {
        __syncthreads();
        #pragma unroll
        for (int mm = 0; mm < 16; ++mm)
            ared[wave][mm][l] = acc[mc*16 + mm];
        __syncthreads();
        for (int q = threadIdx.x; q < 16*64; q += 256) {
            int mm = q >> 6, dl = q & 63;
            float s = ared[0][mm][dl] + ared[1][mm][dl]
                    + ared[2][mm][dl] + ared[3][mm][dl];
            acc_part[((size_t)bid*MM + mc*16 + mm)*HDH + dl] = s;
        }
    }
}

// ---- combine dispatch partials: y[b,m,h*64+d] = sum_c acc / sum_c pl
__global__ __launch_bounds__(64) void k_disp_combine(const float* __restrict__ pl_part,
        const float* __restrict__ acc_part, float* __restrict__ y) {
    int bid = blockIdx.x;                 // B*H*M
    int b   = bid / (HH*MM);
    int rem = bid % (HH*MM);
    int h   = rem / MM;
    int m   = rem % MM;
    int l   = threadIdx.x;
    float pl = 0.f, a = 0.f;
    #pragma unroll
    for (int c = 0; c < CCH; ++c) {
        int pbid = (b*HH + h)*CCH + c;
        pl += pl_part[(size_t)pbid*MM + m];
        a  += acc_part[((size_t)pbid*MM + m)*HDH + l];
    }
    y[((size_t)b*MM + m)*DD + h*HDH + l] = a / pl;
}

// ---- fc1 (no bias/act here; partial-K atomics into zeroed h1)
__global__ __launch_bounds__(256) void k_fc1(const float* __restrict__ w1,
        const float* __restrict__ y, float* __restrict__ h1) {
    int bid = blockIdx.x;                 // M * 3 * ISPL
    int m   = bid / (3*ISPL);
    int rem = bid % (3*ISPL);
    int och = rem / ISPL;
    int iq  = rem % ISPL;
    int obase = och * 1024;
    int ibase = iq * KI;
    int t = threadIdx.x;

    __shared__ float yT[KI][8];
    if (t < KI) {
        #pragma unroll
        for (int b = 0; b < 8; ++b)
            yT[t][b] = y[((size_t)b*MM + m)*DD + ibase + t];
    }
    __syncthreads();

    float acc[8][4];
    #pragma unroll
    for (int b = 0; b < 8; ++b)
        #pragma unroll
        for (int j = 0; j < 4; ++j) acc[b][j] = 0.f;

    const float* wp = w1 + ((size_t)m*DD + ibase)*FFN + obase + 4*t;
    for (int i = 0; i < KI; ++i) {
        float4 wv = *(const float4*)wp;
        wp += FFN;
        #pragma unroll
        for (int b = 0; b < 8; ++b) {
            float yv = yT[i][b];
            acc[b][0] += yv * wv.x;
            acc[b][1] += yv * wv.y;
            acc[b][2] += yv * wv.z;
            acc[b][3] += yv * wv.w;
        }
    }
    #pragma unroll
    for (int b = 0; b < 8; ++b) {
        float* hp = &h1[((size_t)b*MM + m)*FFN + obase + 4*t];
        #pragma unroll
        for (int j = 0; j < 4; ++j) atomicAdd(hp + j, acc[b][j]);
    }
}

// ---- fc2: load = gelu(h1 + fc1_b); partial-O atomics into zeroed y2 (fc2 bias added in combine)
__global__ __launch_bounds__(192) void k_fc2(const float* __restrict__ w2,
        const float* __restrict__ h1, const float* __restrict__ b1,
        float* __restrict__ y2) {
    int bid = blockIdx.x;                 // M * OSPL
    int m   = bid / OSPL;
    int oq  = bid % OSPL;
    int obase = oq * KO;
    int t = threadIdx.x;                  // 0..191

    __shared__ float gT[KO][8];
    #pragma unroll
    for (int b = 0; b < 8; ++b) {
        float v = h1[((size_t)b*MM + m)*FFN + obase + t] + b1[(size_t)m*FFN + obase + t];
        gT[t][b] = 0.5f * v * (1.0f + erff(v * 0.70710678118654752f));
    }
    __syncthreads();

    float acc[8][4];
    #pragma unroll
    for (int b = 0; b < 8; ++b)
        #pragma unroll
        for (int j = 0; j < 4; ++j) acc[b][j] = 0.f;

    const float* wp = w2 + ((size_t)m*FFN + obase)*DD + 4*t;
    for (int i = 0; i < KO; ++i) {
        float4 wv = *(const float4*)wp;
        wp += DD;
        #pragma unroll
        for (int b = 0; b < 8; ++b) {
            float gv = gT[i][b];
            acc[b][0] += gv * wv.x;
            acc[b][1] += gv * wv.y;
            acc[b][2] += gv * wv.z;
            acc[b][3] += gv * wv.w;
        }
    }
    #pragma unroll
    for (int b = 0; b < 8; ++b) {
        float* yp = &y2[((size_t)b*MM + m)*DD + 4*t];
        #pragma unroll
        for (int j = 0; j < 4; ++j) atomicAdd(yp + j, acc[b][j]);
    }
}

// ---- combine attention: out[b,s,h*64+d] = softmax_m(nt . sl) . (y2h + b2h)
__global__ __launch_bounds__(256) void k_combine(const float* __restrict__ x,
        const float* __restrict__ sl, const float* __restrict__ nw,
        const float* __restrict__ fnt, const float* __restrict__ y2,
        const float* __restrict__ b2, float* __restrict__ out) {
    int bid = blockIdx.x;                 // B*H*(S/TS4)
    const int nc = SS / TS4;              // 16
    int b   = bid / (HH*nc);
    int rem = bid % (HH*nc);
    int h   = rem / nc;
    int cs  = rem % nc;
    int wave = threadIdx.x >> 6;
    int l    = threadIdx.x & 63;

    __shared__ float y2T[64][64];
    for (int q = threadIdx.x; q < 4096; q += 256) {
        int m = q >> 6, d = q & 63;
        y2T[m][d] = y2[((size_t)b*MM + m)*DD + h*HDH + d] + b2[(size_t)m*DD + h*HDH + d];
    }
    float slreg[64];
    #pragma unroll
    for (int k = 0; k < 16; ++k) {
        const float4 v = *(const float4*)&sl[(size_t)l*DD + h*HDH + 4*k];
        slreg[4*k+0] = v.x; slreg[4*k+1] = v.y;
        slreg[4*k+2] = v.z; slreg[4*k+3] = v.w;
    }
    float wl = nw[h*HDH + l];
    __syncthreads();

    for (int ti = wave; ti < TS4; ti += 4) {
        int t = b*SS + cs*TS4 + ti;
        float ntv = x[(size_t)t*DD + h*HDH + l] * wl * fnt[t];
        float lg = 0.f;
        #pragma unroll
        for (int j = 0; j < 64; ++j)
            lg += slreg[j] * __shfl(ntv, j, 64);   // lane l: logit[slot l]
        float p = expf(lg);                         // |lg| <= 1, no max needed
        float tot = wave_reduce_sum(p);
        float pn = p / tot;
        float ov = 0.f;
        #pragma unroll
        for (int m = 0; m < 64; ++m)
            ov += __shfl(pn, m, 64) * y2T[m][l];
        out[(size_t)t*DD + h*HDH + l] = ov;
    }
}

extern "C" void kernel_launch(void* const* d_in, const int* in_sizes, int n_in,
                              void* d_out, int out_size, void* d_ws, size_t ws_size,
                              hipStream_t stream) {
    const float* x     = (const float*)d_in[0];
    const float* slots = (const float*)d_in[1];
    const float* scale = (const float*)d_in[2];
    const float* w1    = (const float*)d_in[3];
    const float* b1    = (const float*)d_in[4];
    const float* w2    = (const float*)d_in[5];
    const float* b2    = (const float*)d_in[6];
    const float* nw    = (const float*)d_in[7];
    float* out = (float*)d_out;

    float* ws   = (float*)d_ws;
    float* sl   = ws;                         // M*D            = 49152
    float* frms = sl   + MM*DD;               // B*S            = 32768
    float* fnt  = frms + BB*SS;               // B*S            = 32768
    float* y    = fnt  + BB*SS;               // B*M*D          = 393216
    float* h1   = y    + (size_t)BB*MM*DD;    // B*M*FFN        = 1572864
    float* y2   = h1   + (size_t)BB*MM*FFN;   // B*M*D          = 393216
    float* plp  = y2   + (size_t)BB*MM*DD;    // B*H*CCH*M      = 49152
    float* accp = plp  + (size_t)BB*HH*CCH*MM;// B*H*CCH*M*HD   = 3145728
    // total ~ 5.67M floats = 22.7 MB

    hipMemsetAsync(h1, 0, sizeof(float)*(size_t)BB*MM*FFN, stream);
    hipMemsetAsync(y2, 0, sizeof(float)*(size_t)BB*MM*DD, stream);

    k_slots<<<MM, 64, 0, stream>>>(slots, scale, sl);
    k_tok<<<BB*SS/4, 256, 0, stream>>>(x, nw, frms, fnt);
    k_dispatch<<<BB*HH*CCH, 256, 0, stream>>>(x, sl, nw, frms, fnt, plp, accp);
    k_disp_combine<<<BB*HH*MM, 64, 0, stream>>>(plp, accp, y);
    k_fc1<<<MM*3*ISPL, 256, 0, stream>>>(w1, y, h1);
    k_fc2<<<MM*OSPL, 192, 0, stream>>>(w2, h1, b1, y2);
    k_combine<<<BB*HH*(SS/TS4), 256, 0, stream>>>(x, sl, nw, fnt, y2, b2, out);
}